// Round 2
// baseline (80.328 us; speedup 1.0000x reference)
//
#include <hip/hip_runtime.h>
#include <hip/hip_bf16.h>

// TT-embedding: VOC = 100*100*100, EMB = 4*4*8, RANK = 16, PAD_IDX = 0.
// core0 [1,100,4,16], core1 [16,100,4,16], core2 [16,100,8,1]  (float32)
// x [64,512] int32 indices; out [64,512,128] float32.
//
// emb[j1,j2,j3] = sum_{r1,r2} A(i1)[j1,r1] * B(i2)[r1,j2,r2] * C(i3)[r2,j3]
// Factored: M[r1,j2,j3] = sum_r2 B*C (8192 MAC/token), emb = sum_r1 A*M (2048 MAC/token).

// Per-wave LDS region: As[64] | Cs[128] | Ms[512] = 704 floats (2816 B); 4 waves -> 11264 B/block
#define LDS_PER_WAVE 704

__global__ __launch_bounds__(256) void tt_embed_kernel(
    const int* __restrict__ x,
    const float* __restrict__ c0,   // [100,4,16]
    const float* __restrict__ c1,   // [16,100,4,16]
    const float* __restrict__ c2,   // [16,100,8]
    float* __restrict__ out,        // [nTok,128]
    int nTok)
{
    __shared__ float lds[4 * LDS_PER_WAVE];
    const int wave = threadIdx.x >> 6;
    const int lane = threadIdx.x & 63;
    const int t = blockIdx.x * 4 + wave;
    const bool active = (t < nTok);

    float* As = lds + wave * LDS_PER_WAVE;        // 64 floats
    float* Cs = As + 64;                          // 128 floats
    float* Ms = Cs + 128;                         // 512 floats

    int idx = 0;
    if (active) idx = x[t];
    const int i1 = idx / 10000;
    const int rem = idx - i1 * 10000;
    const int i2 = rem / 100;
    const int i3 = rem - i2 * 100;

    // ---- Stage 0: stage A (core0[i1,:,:], 64 f32) and C (core2[:,i3,:], 16x8 f32) into LDS
    if (active) {
        if (lane < 16) {
            // As: 16 lanes x float4 = 64 floats
            ((float4*)As)[lane] = *(const float4*)(c0 + i1 * 64 + lane * 4);
        } else if (lane < 48) {
            // Cs: 32 lanes x float4 = 128 floats ; row r2 = 8 floats = 2 float4
            const int l = lane - 16;
            const int r2 = l >> 1;
            const int half = l & 1;
            ((float4*)Cs)[l] = *(const float4*)(c2 + (r2 * 100 + i3) * 8 + half * 4);
        }
    }

    // ---- This lane's B row: core1[r1, i2, j2, 0..15]  (r1 = lane>>2, j2 = lane&3)
    const int r1 = lane >> 2;
    const int j2 = lane & 3;
    float bb[16];
    if (active) {
        const float4* bp = (const float4*)(c1 + ((r1 * 100 + i2) * 4 + j2) * 16);
        float4 b0 = bp[0], b1 = bp[1], b2 = bp[2], b3 = bp[3];
        bb[0]=b0.x; bb[1]=b0.y; bb[2]=b0.z; bb[3]=b0.w;
        bb[4]=b1.x; bb[5]=b1.y; bb[6]=b1.z; bb[7]=b1.w;
        bb[8]=b2.x; bb[9]=b2.y; bb[10]=b2.z; bb[11]=b2.w;
        bb[12]=b3.x; bb[13]=b3.y; bb[14]=b3.z; bb[15]=b3.w;
    } else {
        #pragma unroll
        for (int j = 0; j < 16; ++j) bb[j] = 0.0f;
    }

    __syncthreads();   // As/Cs visible

    // ---- Stage 1: M[r1, j2, 0..7] = sum_r2 bb[r2] * Cs[r2*8 + 0..7]
    float mv[8];
    #pragma unroll
    for (int j = 0; j < 8; ++j) mv[j] = 0.0f;
    #pragma unroll
    for (int r2 = 0; r2 < 16; ++r2) {
        const float4* cp = (const float4*)(Cs + r2 * 8);   // wave-uniform addr -> broadcast
        float4 ca = cp[0];
        float4 cb = cp[1];
        const float b = bb[r2];
        mv[0] += b * ca.x; mv[1] += b * ca.y; mv[2] += b * ca.z; mv[3] += b * ca.w;
        mv[4] += b * cb.x; mv[5] += b * cb.y; mv[6] += b * cb.z; mv[7] += b * cb.w;
    }
    // M flat index m = r1*32 + j2*8 + j3 == lane*8 + j3
    {
        float4* mp = (float4*)(Ms + lane * 8);
        mp[0] = make_float4(mv[0], mv[1], mv[2], mv[3]);
        mp[1] = make_float4(mv[4], mv[5], mv[6], mv[7]);
    }

    __syncthreads();   // Ms visible

    // ---- Stage 2: each lane produces adjacent outputs e0 = 2*lane, e0+1
    const int e0 = lane * 2;
    const int j1 = e0 >> 5;          // 0..3
    const int mcol = e0 & 31;        // (j2*8 + j3), even

    const float4* ap = (const float4*)(As + j1 * 16);
    float4 a0 = ap[0], a1 = ap[1], a2 = ap[2], a3 = ap[3];
    float av[16] = { a0.x, a0.y, a0.z, a0.w, a1.x, a1.y, a1.z, a1.w,
                     a2.x, a2.y, a2.z, a2.w, a3.x, a3.y, a3.z, a3.w };

    float o0 = 0.0f, o1 = 0.0f;
    #pragma unroll
    for (int r = 0; r < 16; ++r) {
        const float2 m = *(const float2*)(Ms + r * 32 + mcol);
        o0 += av[r] * m.x;
        o1 += av[r] * m.y;
    }

    if (idx == 0) { o0 = 0.0f; o1 = 0.0f; }   // PAD_IDX -> zero row

    if (active) {
        *(float2*)(out + (long)t * 128 + e0) = make_float2(o0, o1);
    }
}

extern "C" void kernel_launch(void* const* d_in, const int* in_sizes, int n_in,
                              void* d_out, int out_size, void* d_ws, size_t ws_size,
                              hipStream_t stream) {
    const int*   x  = (const int*)d_in[0];
    const float* c0 = (const float*)d_in[1];
    const float* c1 = (const float*)d_in[2];
    const float* c2 = (const float*)d_in[3];
    float* out = (float*)d_out;

    const int nTok = out_size / 128;           // 64*512 = 32768
    const int blocks = (nTok + 3) / 4;         // one wave per token, 4 waves/block
    tt_embed_kernel<<<dim3(blocks), dim3(256), 0, stream>>>(x, c0, c1, c2, out, nTok);
}